// Round 6
// baseline (2280.176 us; speedup 1.0000x reference)
//
#include <hip/hip_runtime.h>

// Comb filter: y[n] = x[n-D] + f*y[n-D], y[n]=0 for n<D.
// N = 16777216, D = 4096 -> 4096 independent chains of K = 4096 steps each.
//
// SINGLE-PASS decoupled-lookback scan (rocPRIM pattern), no grid sync:
//   - 1024 blocks, 256 threads, float2/thread (VGPR ~100 -> 16 waves/CU).
//   - Block takes execution-ordered rank via atomic ticket -> rank r
//     processes (segment s = r>>3, chain-group g = r&7). Predecessor ranks
//     are already running/finished -> spin-wait is deadlock-free.
//   - Phase 1 (dependency-free): preload 32 float2 of x into regs, Horner
//     carry C_s, publish to ws + release flag.
//   - Phase 2: Y_s = sum_{t<s} fL^(s-1-t) C_t (order-free weighted sum,
//     fixed association -> deterministic bits), acquiring flags in windows
//     of 4; flags are set within the first few us so spins exit immediately.
//   - Phase 3: replay exact recurrence from Y_s using register-resident x.
// x is read from HBM exactly ONCE (R4/R5 read it twice).
// ws layout: [0] ticket | [64B..] 1024 flags | [8KB..] carries (2 MiB).

#define N_TOTAL 16777216
#define D       4096
#define K_STEPS (N_TOTAL / D)    // 4096
#define SEGS    128              // segments per chain
#define SEGLEN  (K_STEPS / SEGS) // 32 steps per segment
#define D2      (D / 2)          // 2048 float2 per k-row
#define D4      (D / 4)          // 1024 float4 per k-row
#define GROUPS  8                // chain-groups per segment row (float2 path)
#define WS_FLAGS_OFF   16        // uints (64 B)
#define WS_CARRY_OFF   8192      // bytes
#define WS_NEEDED      (WS_CARRY_OFF + SEGS * D * 4)

__global__ __launch_bounds__(256, 4)   // 4 waves/EU -> 16 waves/CU, VGPR <= 128
void comb_fused(const float* __restrict__ x, const float* __restrict__ fptr,
                float* __restrict__ out, unsigned int* __restrict__ ws_u32,
                float* __restrict__ carries) {
    unsigned int* ticket = ws_u32;
    unsigned int* flags  = ws_u32 + WS_FLAGS_OFF;

    __shared__ unsigned int s_rank;
    if (threadIdx.x == 0)
        s_rank = __hip_atomic_fetch_add(ticket, 1u, __ATOMIC_RELAXED,
                                        __HIP_MEMORY_SCOPE_AGENT);
    __syncthreads();
    const unsigned int rank = s_rank;
    const int s = rank >> 3;                    // 0..127
    const int g = rank & 7;                     // 0..7
    const int c2 = g * 256 + threadIdx.x;       // float2 chain index 0..2047

    const float f = fptr[0];
    const float2* __restrict__ xp = (const float2*)x;
    float2* __restrict__ op = (float2*)out;
    const int base = s * SEGLEN * D2 + c2;

    // ---- Phase 1: preload x into regs, local carry, publish ----
    float2 xa[SEGLEN];
    #pragma unroll
    for (int k = 0; k < SEGLEN; ++k) xa[k] = xp[base + k * D2];

    float2 C = make_float2(0.f, 0.f);
    #pragma unroll
    for (int k = 0; k < SEGLEN; ++k) {
        C.x = f * C.x + xa[k].x;
        C.y = f * C.y + xa[k].y;
    }
    ((float2*)carries)[s * D2 + c2] = C;
    __syncthreads();
    if (threadIdx.x == 0) {
        __threadfence();
        __hip_atomic_store(&flags[s * GROUPS + g], 1u, __ATOMIC_RELEASE,
                           __HIP_MEMORY_SCOPE_AGENT);
    }

    // fL = f^SEGLEN via 5 squarings (SEGLEN = 32)
    float fL = f * f;
    fL = fL * fL; fL = fL * fL; fL = fL * fL; fL = fL * fL;
    const float fL2 = fL * fL;
    const float fL4 = fL2 * fL2;

    // ---- Phase 2: order-free weighted lookback (fixed association) ----
    const float2* __restrict__ cp = (const float2*)carries;
    float2 Y0 = make_float2(0.f, 0.f), Y1 = Y0, Y2 = Y0, Y3 = Y0;
    float w = 1.f;
    int t = s - 1;
    for (; t >= 3; t -= 4) {
        for (;;) {
            unsigned int f0 = __hip_atomic_load(&flags[(t    ) * GROUPS + g], __ATOMIC_ACQUIRE, __HIP_MEMORY_SCOPE_AGENT);
            unsigned int f1 = __hip_atomic_load(&flags[(t - 1) * GROUPS + g], __ATOMIC_ACQUIRE, __HIP_MEMORY_SCOPE_AGENT);
            unsigned int f2 = __hip_atomic_load(&flags[(t - 2) * GROUPS + g], __ATOMIC_ACQUIRE, __HIP_MEMORY_SCOPE_AGENT);
            unsigned int f3 = __hip_atomic_load(&flags[(t - 3) * GROUPS + g], __ATOMIC_ACQUIRE, __HIP_MEMORY_SCOPE_AGENT);
            if (f0 & f1 & f2 & f3) break;
        }
        float2 C0 = cp[(t    ) * D2 + c2];
        float2 C1 = cp[(t - 1) * D2 + c2];
        float2 C2 = cp[(t - 2) * D2 + c2];
        float2 C3 = cp[(t - 3) * D2 + c2];
        const float w0 = w, w1 = w * fL, w2 = w * fL2, w3 = w1 * fL2;
        Y0.x += w0 * C0.x; Y0.y += w0 * C0.y;
        Y1.x += w1 * C1.x; Y1.y += w1 * C1.y;
        Y2.x += w2 * C2.x; Y2.y += w2 * C2.y;
        Y3.x += w3 * C3.x; Y3.y += w3 * C3.y;
        w = w * fL4;
    }
    for (; t >= 0; --t) {
        while (!__hip_atomic_load(&flags[t * GROUPS + g], __ATOMIC_ACQUIRE,
                                  __HIP_MEMORY_SCOPE_AGENT)) {}
        float2 Ct = cp[t * D2 + c2];
        Y0.x += w * Ct.x; Y0.y += w * Ct.y;
        w *= fL;
    }
    float2 y;
    y.x = (Y0.x + Y1.x) + (Y2.x + Y3.x);
    y.y = (Y0.y + Y1.y) + (Y2.y + Y3.y);

    // ---- Phase 3: replay exact recurrence from Y_s, write y ----
    #pragma unroll
    for (int k = 0; k < SEGLEN; ++k) {
        op[base + k * D2] = y;
        y.x = f * y.x + xa[k].x;
        y.y = f * y.y + xa[k].y;
    }
}

// ---------- Fallback (verified R4 path) if ws_size is too small ----------
__device__ float g_carry[SEGS * D];

__global__ __launch_bounds__(256)
void comb_carry(const float* __restrict__ x, const float* __restrict__ fptr) {
    const float f = fptr[0];
    const int c4 = (blockIdx.x & 3) * 256 + threadIdx.x;
    const int s  = blockIdx.x >> 2;
    const float4* __restrict__ xp = (const float4*)x;
    const int base = s * SEGLEN * D4 + c4;
    float4 acc = make_float4(0.f, 0.f, 0.f, 0.f);
    #pragma unroll 8
    for (int k = 0; k < SEGLEN; ++k) {
        float4 a = xp[base + k * D4];
        acc.x = f * acc.x + a.x; acc.y = f * acc.y + a.y;
        acc.z = f * acc.z + a.z; acc.w = f * acc.w + a.w;
    }
    ((float4*)g_carry)[s * D4 + c4] = acc;
}

__global__ __launch_bounds__(256)
void comb_scan_emit(const float* __restrict__ x, const float* __restrict__ fptr,
                    float* __restrict__ out) {
    const float f = fptr[0];
    const int c4 = (blockIdx.x & 3) * 256 + threadIdx.x;
    const int s  = blockIdx.x >> 2;
    const float4* __restrict__ xp = (const float4*)x;
    float4* __restrict__ op = (float4*)out;
    const int base = s * SEGLEN * D4 + c4;
    float4 xa[SEGLEN];
    #pragma unroll
    for (int k = 0; k < SEGLEN; ++k) xa[k] = xp[base + k * D4];
    float fL = f * f; fL = fL * fL; fL = fL * fL; fL = fL * fL; fL = fL * fL;
    const float fL2 = fL * fL, fL4 = fL2 * fL2;
    const float4* __restrict__ cp = (const float4*)g_carry;
    float4 Y0 = make_float4(0.f, 0.f, 0.f, 0.f), Y1 = Y0, Y2 = Y0, Y3 = Y0;
    float w = 1.f;
    int t = s - 1;
    #pragma unroll 4
    for (; t >= 3; t -= 4) {
        float4 C0 = cp[(t    ) * D4 + c4];
        float4 C1 = cp[(t - 1) * D4 + c4];
        float4 C2 = cp[(t - 2) * D4 + c4];
        float4 C3 = cp[(t - 3) * D4 + c4];
        const float w0 = w, w1 = w * fL, w2 = w * fL2, w3 = w1 * fL2;
        Y0.x += w0 * C0.x; Y0.y += w0 * C0.y; Y0.z += w0 * C0.z; Y0.w += w0 * C0.w;
        Y1.x += w1 * C1.x; Y1.y += w1 * C1.y; Y1.z += w1 * C1.z; Y1.w += w1 * C1.w;
        Y2.x += w2 * C2.x; Y2.y += w2 * C2.y; Y2.z += w2 * C2.z; Y2.w += w2 * C2.w;
        Y3.x += w3 * C3.x; Y3.y += w3 * C3.y; Y3.z += w3 * C3.z; Y3.w += w3 * C3.w;
        w = w * fL4;
    }
    for (; t >= 0; --t) {
        float4 Ct = cp[t * D4 + c4];
        Y0.x += w * Ct.x; Y0.y += w * Ct.y; Y0.z += w * Ct.z; Y0.w += w * Ct.w;
        w *= fL;
    }
    float4 y;
    y.x = (Y0.x + Y1.x) + (Y2.x + Y3.x);
    y.y = (Y0.y + Y1.y) + (Y2.y + Y3.y);
    y.z = (Y0.z + Y1.z) + (Y2.z + Y3.z);
    y.w = (Y0.w + Y1.w) + (Y2.w + Y3.w);
    #pragma unroll
    for (int k = 0; k < SEGLEN; ++k) {
        op[base + k * D4] = y;
        y.x = f * y.x + xa[k].x; y.y = f * y.y + xa[k].y;
        y.z = f * y.z + xa[k].z; y.w = f * y.w + xa[k].w;
    }
}

extern "C" void kernel_launch(void* const* d_in, const int* in_sizes, int n_in,
                              void* d_out, int out_size, void* d_ws, size_t ws_size,
                              hipStream_t stream) {
    const float* x = (const float*)d_in[0];
    const float* f = (const float*)d_in[1];
    float* out = (float*)d_out;
    (void)in_sizes; (void)n_in; (void)out_size;

    if (ws_size >= (size_t)WS_NEEDED) {
        // zero ticket + flags (first 8 KB); carries need no init (write-before-read)
        hipMemsetAsync(d_ws, 0, WS_CARRY_OFF, stream);
        unsigned int* ws_u32 = (unsigned int*)d_ws;
        float* carries = (float*)((char*)d_ws + WS_CARRY_OFF);
        comb_fused<<<dim3(SEGS * GROUPS), dim3(256), 0, stream>>>(
            x, f, out, ws_u32, carries);
    } else {
        dim3 blk(256);
        comb_carry<<<dim3(SEGS * 4), blk, 0, stream>>>(x, f);
        comb_scan_emit<<<dim3(SEGS * 4), blk, 0, stream>>>(x, f, out);
    }
}

// Round 7
// 80.515 us; speedup vs baseline: 28.3201x; 28.3201x over previous
//
#include <hip/hip_runtime.h>

// Comb filter: y[n] = x[n-D] + f*y[n-D], y[n]=0 for n<D.
// N = 16777216, D = 4096 -> 4096 independent chains of K = 4096 steps each.
//
// SINGLE-PASS decoupled-lookback scan, cross-XCD-safe WITHOUT acquire/release
// in loops (R6 lesson: acquire-polls caused an invalidate storm -> 2.3 ms):
//   - All cross-block data (carries, flags) moves via RELAXED agent-scope
//     atomics -> sc0/sc1 loads/stores that bypass L1/L2 to the coherent L3.
//     No buffer_inv anywhere. Stale local L2 lines are never consulted.
//   - Carry stores are drained by __syncthreads (s_waitcnt vmcnt(0) before
//     s_barrier) BEFORE t0 publishes the flag -> data at L3 before flag.
//   - Only WAVE 0 polls flags (2 flags/lane, __all ballot, s_sleep backoff);
//     other waves park at __syncthreads.
//   - Lookback is the order-free weighted sum (descending t, 4 accumulators,
//     fixed association) -> deterministic bits, same math as R4/R5/R6.
// x is read from HBM exactly once and stays in registers for the emit.
// ws layout: [0] ticket | [64B..] 1024 flags | [8KB..] carries (2 MiB).

#define N_TOTAL 16777216
#define D       4096
#define K_STEPS (N_TOTAL / D)    // 4096
#define SEGS    128              // segments per chain
#define SEGLEN  (K_STEPS / SEGS) // 32 steps per segment
#define D2      (D / 2)          // 2048 float2 per k-row
#define D4      (D / 4)          // 1024 float4 per k-row
#define GROUPS  8                // chain-groups per segment row (float2 path)
#define WS_FLAGS_OFF   16        // in u32s (64 B)
#define WS_CARRY_OFF   8192      // bytes
#define WS_NEEDED      (WS_CARRY_OFF + SEGS * D * 4)

__device__ __forceinline__ float2 u64_to_f2(unsigned long long r) {
    float2 v; __builtin_memcpy(&v, &r, 8); return v;
}

__global__ __launch_bounds__(256, 4)   // cap VGPR at 128 -> 4 blocks/CU min
void comb_fused(const float* __restrict__ x, const float* __restrict__ fptr,
                float* __restrict__ out, unsigned int* __restrict__ ws_u32,
                unsigned long long* __restrict__ carries) {
    unsigned int* ticket = ws_u32;
    unsigned int* flags  = ws_u32 + WS_FLAGS_OFF;

    __shared__ unsigned int s_rank;
    if (threadIdx.x == 0)
        s_rank = __hip_atomic_fetch_add(ticket, 1u, __ATOMIC_RELAXED,
                                        __HIP_MEMORY_SCOPE_AGENT);
    __syncthreads();
    const unsigned int rank = s_rank;
    const int s  = rank >> 3;                   // 0..127
    const int g  = rank & 7;                    // 0..7
    const int c2 = g * 256 + threadIdx.x;       // float2 chain index 0..2047

    const float f = fptr[0];
    const float2* __restrict__ xp = (const float2*)x;
    float2* __restrict__ op = (float2*)out;
    const int base = s * SEGLEN * D2 + c2;

    // ---- Phase 1: preload x into regs, local carry, publish (bypass L2) ----
    float2 xa[SEGLEN];
    #pragma unroll
    for (int k = 0; k < SEGLEN; ++k) xa[k] = xp[base + k * D2];

    float2 C = make_float2(0.f, 0.f);
    #pragma unroll
    for (int k = 0; k < SEGLEN; ++k) {
        C.x = f * C.x + xa[k].x;
        C.y = f * C.y + xa[k].y;
    }
    unsigned long long craw;
    __builtin_memcpy(&craw, &C, 8);
    __hip_atomic_store(&carries[s * D2 + c2], craw, __ATOMIC_RELAXED,
                       __HIP_MEMORY_SCOPE_AGENT);
    __syncthreads();   // drains vmcnt -> all carry stores complete at L3
    if (threadIdx.x == 0)
        __hip_atomic_store(&flags[s * GROUPS + g], 1u, __ATOMIC_RELEASE,
                           __HIP_MEMORY_SCOPE_AGENT);

    // fL = f^SEGLEN via 5 squarings (SEGLEN = 32)
    float fL = f * f;
    fL = fL * fL; fL = fL * fL; fL = fL * fL; fL = fL * fL;
    const float fL2 = fL * fL;
    const float fL4 = fL2 * fL2;

    // ---- Wave-0 cooperative poll: 2 flags/lane, relaxed bypass loads ----
    if (threadIdx.x < 64 && s > 0) {
        const int l = threadIdx.x;
        for (;;) {
            bool ok0 = (l >= s) ||
                (__hip_atomic_load(&flags[l * GROUPS + g], __ATOMIC_RELAXED,
                                   __HIP_MEMORY_SCOPE_AGENT) != 0u);
            bool ok1 = (l + 64 >= s) ||
                (__hip_atomic_load(&flags[(l + 64) * GROUPS + g], __ATOMIC_RELAXED,
                                   __HIP_MEMORY_SCOPE_AGENT) != 0u);
            if (__all(ok0 && ok1)) break;
            __builtin_amdgcn_s_sleep(2);
        }
    }
    __syncthreads();   // data loads below cannot be hoisted above the poll

    // ---- Phase 2: order-free weighted lookback (fixed association) ----
    float2 Y0 = make_float2(0.f, 0.f), Y1 = Y0, Y2 = Y0, Y3 = Y0;
    float w = 1.f;
    int t = s - 1;
    for (; t >= 3; t -= 4) {
        unsigned long long r0 = __hip_atomic_load(&carries[(t    ) * D2 + c2], __ATOMIC_RELAXED, __HIP_MEMORY_SCOPE_AGENT);
        unsigned long long r1 = __hip_atomic_load(&carries[(t - 1) * D2 + c2], __ATOMIC_RELAXED, __HIP_MEMORY_SCOPE_AGENT);
        unsigned long long r2 = __hip_atomic_load(&carries[(t - 2) * D2 + c2], __ATOMIC_RELAXED, __HIP_MEMORY_SCOPE_AGENT);
        unsigned long long r3 = __hip_atomic_load(&carries[(t - 3) * D2 + c2], __ATOMIC_RELAXED, __HIP_MEMORY_SCOPE_AGENT);
        float2 C0 = u64_to_f2(r0), C1 = u64_to_f2(r1);
        float2 C2 = u64_to_f2(r2), C3 = u64_to_f2(r3);
        const float w0 = w, w1 = w * fL, w2 = w * fL2, w3 = w1 * fL2;
        Y0.x += w0 * C0.x; Y0.y += w0 * C0.y;
        Y1.x += w1 * C1.x; Y1.y += w1 * C1.y;
        Y2.x += w2 * C2.x; Y2.y += w2 * C2.y;
        Y3.x += w3 * C3.x; Y3.y += w3 * C3.y;
        w = w * fL4;
    }
    for (; t >= 0; --t) {
        unsigned long long rr = __hip_atomic_load(&carries[t * D2 + c2], __ATOMIC_RELAXED, __HIP_MEMORY_SCOPE_AGENT);
        float2 Ct = u64_to_f2(rr);
        Y0.x += w * Ct.x; Y0.y += w * Ct.y;
        w *= fL;
    }
    float2 y;
    y.x = (Y0.x + Y1.x) + (Y2.x + Y3.x);
    y.y = (Y0.y + Y1.y) + (Y2.y + Y3.y);

    // ---- Phase 3: replay exact recurrence from Y_s, write y ----
    #pragma unroll
    for (int k = 0; k < SEGLEN; ++k) {
        op[base + k * D2] = y;
        y.x = f * y.x + xa[k].x;
        y.y = f * y.y + xa[k].y;
    }
}

// ---------- Fallback (verified R4 path, 36 us) if ws_size is too small ----------
__device__ float g_carry[SEGS * D];

__global__ __launch_bounds__(256)
void comb_carry(const float* __restrict__ x, const float* __restrict__ fptr) {
    const float f = fptr[0];
    const int c4 = (blockIdx.x & 3) * 256 + threadIdx.x;
    const int s  = blockIdx.x >> 2;
    const float4* __restrict__ xp = (const float4*)x;
    const int base = s * SEGLEN * D4 + c4;
    float4 acc = make_float4(0.f, 0.f, 0.f, 0.f);
    #pragma unroll 8
    for (int k = 0; k < SEGLEN; ++k) {
        float4 a = xp[base + k * D4];
        acc.x = f * acc.x + a.x; acc.y = f * acc.y + a.y;
        acc.z = f * acc.z + a.z; acc.w = f * acc.w + a.w;
    }
    ((float4*)g_carry)[s * D4 + c4] = acc;
}

__global__ __launch_bounds__(256)
void comb_scan_emit(const float* __restrict__ x, const float* __restrict__ fptr,
                    float* __restrict__ out) {
    const float f = fptr[0];
    const int c4 = (blockIdx.x & 3) * 256 + threadIdx.x;
    const int s  = blockIdx.x >> 2;
    const float4* __restrict__ xp = (const float4*)x;
    float4* __restrict__ op = (float4*)out;
    const int base = s * SEGLEN * D4 + c4;
    float4 xa[SEGLEN];
    #pragma unroll
    for (int k = 0; k < SEGLEN; ++k) xa[k] = xp[base + k * D4];
    float fL = f * f; fL = fL * fL; fL = fL * fL; fL = fL * fL; fL = fL * fL;
    const float fL2 = fL * fL, fL4 = fL2 * fL2;
    const float4* __restrict__ cp = (const float4*)g_carry;
    float4 Y0 = make_float4(0.f, 0.f, 0.f, 0.f), Y1 = Y0, Y2 = Y0, Y3 = Y0;
    float w = 1.f;
    int t = s - 1;
    #pragma unroll 4
    for (; t >= 3; t -= 4) {
        float4 C0 = cp[(t    ) * D4 + c4];
        float4 C1 = cp[(t - 1) * D4 + c4];
        float4 C2 = cp[(t - 2) * D4 + c4];
        float4 C3 = cp[(t - 3) * D4 + c4];
        const float w0 = w, w1 = w * fL, w2 = w * fL2, w3 = w1 * fL2;
        Y0.x += w0 * C0.x; Y0.y += w0 * C0.y; Y0.z += w0 * C0.z; Y0.w += w0 * C0.w;
        Y1.x += w1 * C1.x; Y1.y += w1 * C1.y; Y1.z += w1 * C1.z; Y1.w += w1 * C1.w;
        Y2.x += w2 * C2.x; Y2.y += w2 * C2.y; Y2.z += w2 * C2.z; Y2.w += w2 * C2.w;
        Y3.x += w3 * C3.x; Y3.y += w3 * C3.y; Y3.z += w3 * C3.z; Y3.w += w3 * C3.w;
        w = w * fL4;
    }
    for (; t >= 0; --t) {
        float4 Ct = cp[t * D4 + c4];
        Y0.x += w * Ct.x; Y0.y += w * Ct.y; Y0.z += w * Ct.z; Y0.w += w * Ct.w;
        w *= fL;
    }
    float4 y;
    y.x = (Y0.x + Y1.x) + (Y2.x + Y3.x);
    y.y = (Y0.y + Y1.y) + (Y2.y + Y3.y);
    y.z = (Y0.z + Y1.z) + (Y2.z + Y3.z);
    y.w = (Y0.w + Y1.w) + (Y2.w + Y3.w);
    #pragma unroll
    for (int k = 0; k < SEGLEN; ++k) {
        op[base + k * D4] = y;
        y.x = f * y.x + xa[k].x; y.y = f * y.y + xa[k].y;
        y.z = f * y.z + xa[k].z; y.w = f * y.w + xa[k].w;
    }
}

extern "C" void kernel_launch(void* const* d_in, const int* in_sizes, int n_in,
                              void* d_out, int out_size, void* d_ws, size_t ws_size,
                              hipStream_t stream) {
    const float* x = (const float*)d_in[0];
    const float* f = (const float*)d_in[1];
    float* out = (float*)d_out;
    (void)in_sizes; (void)n_in; (void)out_size;

    if (ws_size >= (size_t)WS_NEEDED) {
        // zero ticket + flags (first 8 KB); carries are write-before-read
        hipMemsetAsync(d_ws, 0, WS_CARRY_OFF, stream);
        unsigned int* ws_u32 = (unsigned int*)d_ws;
        unsigned long long* carries =
            (unsigned long long*)((char*)d_ws + WS_CARRY_OFF);
        comb_fused<<<dim3(SEGS * GROUPS), dim3(256), 0, stream>>>(
            x, f, out, ws_u32, carries);
    } else {
        dim3 blk(256);
        comb_carry<<<dim3(SEGS * 4), blk, 0, stream>>>(x, f);
        comb_scan_emit<<<dim3(SEGS * 4), blk, 0, stream>>>(x, f, out);
    }
}